// Round 16
// baseline (249.342 us; speedup 1.0000x reference)
//
#include <hip/hip_runtime.h>

typedef __attribute__((ext_vector_type(8))) __bf16 bf16x8;
typedef __attribute__((ext_vector_type(4))) float f32x4;
typedef __attribute__((ext_vector_type(16))) float f32x16;
typedef unsigned short u16;
typedef unsigned int u32;

#define BB 4
#define SS 2048
#define EE 1024
#define HH 4
#define DD 256

#define GLOAD_LDS(g, l) __builtin_amdgcn_global_load_lds( \
    (const __attribute__((address_space(1))) unsigned int*)(g), \
    (__attribute__((address_space(3))) unsigned int*)(l), 16, 0, 0)

__device__ __forceinline__ u16 f2bf(float f) {
  unsigned int u = __float_as_uint(f);
  u = (u + 0x7FFFu + ((u >> 16) & 1u)) >> 16;   // RNE
  return (u16)u;
}

// ---------------- cast f32 -> bf16 (vectorized) ----------------
__global__ __launch_bounds__(256) void cast_bf16_k(const float* __restrict__ in,
                                                   u16* __restrict__ out, int n4) {
  int i = blockIdx.x * 256 + threadIdx.x;
  if (i >= n4) return;
  float4 v = ((const float4*)in)[i];
  union { u16 s[4]; uint2 u; } o;
  o.s[0] = f2bf(v.x); o.s[1] = f2bf(v.y); o.s[2] = f2bf(v.z); o.s[3] = f2bf(v.w);
  ((uint2*)out)[i] = o.u;
}

// ---------------- transpose + cast: in[R][C] f32 -> out[C][R] bf16 ----------------
// scale_q applied when blockIdx.z < 4 (Q-head weights: fold softmax scale, log2 dom).
__global__ __launch_bounds__(256) void transpose_cast_k(const float* __restrict__ in,
                                                        u16* __restrict__ out, int R, int C,
                                                        float scale_q) {
  __shared__ float tile[32][33];
  size_t moff = (size_t)blockIdx.z * R * C;
  in += moff; out += moff;
  float sc = (blockIdx.z < 4) ? scale_q : 1.0f;
  int c0 = blockIdx.x * 32, r0 = blockIdx.y * 32;
  int tx = threadIdx.x, ty = threadIdx.y;   // 32 x 8
  #pragma unroll
  for (int i = 0; i < 4; ++i)
    tile[ty + 8*i][tx] = in[(size_t)(r0 + ty + 8*i) * C + c0 + tx];
  __syncthreads();
  #pragma unroll
  for (int i = 0; i < 4; ++i)
    out[(size_t)(c0 + ty + 8*i) * R + r0 + tx] = f2bf(tile[tx][ty + 8*i] * sc);
}

// ---------------- 128x128 bf16 GEMM core: C = A[M][K] * Bt[N][K]^T ----------------
__device__ __forceinline__ void gemm128(const u16* __restrict__ A, int lda,
                                        const u16* __restrict__ Bt, int ldb,
                                        int row0, int col0, int K,
                                        u16* As, u16* Bs, f32x4 acc[4][4]) {
  int t = threadIdx.x;
  int lane = t & 63, w = t >> 6;
  int wr = w >> 1, wc = w & 1;
  int lr = lane & 15, kg = lane >> 4;
  f32x4 z = {0.f, 0.f, 0.f, 0.f};
  #pragma unroll
  for (int m = 0; m < 4; ++m)
    #pragma unroll
    for (int n = 0; n < 4; ++n) acc[m][n] = z;
  for (int kt = 0; kt < K; kt += 64) {
    __syncthreads();
    #pragma unroll
    for (int it = 0; it < 4; ++it) {
      int Lb = it*4096 + w*1024 + lane*16;       // dest byte within 128x64 tile
      int row = Lb >> 7;
      int scb = ((Lb >> 4) & 7) ^ (row & 7);     // pre-swizzled source col-block
      GLOAD_LDS(A  + (size_t)(row0 + row) * lda + kt + scb*8,
                (char*)As + it*4096 + w*1024);
      GLOAD_LDS(Bt + (size_t)(col0 + row) * ldb + kt + scb*8,
                (char*)Bs + it*4096 + w*1024);
    }
    __syncthreads();
    __builtin_amdgcn_s_setprio(1);
    #pragma unroll
    for (int kk = 0; kk < 2; ++kk) {
      bf16x8 af[4], bfr[4];
      #pragma unroll
      for (int m = 0; m < 4; ++m) {
        int row = wr*64 + m*16 + lr;
        int bo = (row << 7) + ((((kk << 6) + (kg << 4))) ^ ((row & 7) << 4));
        af[m] = *(const bf16x8*)((const char*)As + bo);
      }
      #pragma unroll
      for (int n = 0; n < 4; ++n) {
        int row = wc*64 + n*16 + lr;
        int bo = (row << 7) + ((((kk << 6) + (kg << 4))) ^ ((row & 7) << 4));
        bfr[n] = *(const bf16x8*)((const char*)Bs + bo);
      }
      #pragma unroll
      for (int m = 0; m < 4; ++m)
        #pragma unroll
        for (int n = 0; n < 4; ++n)
          acc[m][n] = __builtin_amdgcn_mfma_f32_16x16x32_bf16(af[m], bfr[n], acc[m][n], 0, 0, 0);
    }
    __builtin_amdgcn_s_setprio(0);
  }
}

// ---------------- QKV projection (round-12 mapping: mt fast -> XCD-affine A) ----------------
__global__ __launch_bounds__(256) void qkv_gemm_k(const u16* __restrict__ xb,
                                                  const u16* __restrict__ wt,
                                                  u16* __restrict__ qb,
                                                  u16* __restrict__ kp,
                                                  u16* __restrict__ vp) {
  __shared__ u16 As[128*64], Bs[128*64];
  int bid = blockIdx.x;
  int mh = bid >> 7;               // 0..11  (qkvi*4 + h)
  int tt = bid & 127;
  int mt = tt & 63, nt = tt >> 6;  // 64 M-tiles, 2 N-tiles
  f32x4 acc[4][4];
  gemm128(xb, EE, wt + (size_t)mh * DD * EE, EE, mt*128, nt*128, EE, As, Bs, acc);
  int t = threadIdx.x, lane = t & 63, w = t >> 6;
  int wr = w >> 1, wc = w & 1, lr = lane & 15, kg = lane >> 4;
  int qi = mh >> 2, h = mh & 3;
  if (qi == 0) {
    #pragma unroll
    for (int m = 0; m < 4; ++m)
      #pragma unroll
      for (int n = 0; n < 4; ++n)
        #pragma unroll
        for (int j = 0; j < 4; ++j) {
          int r = mt*128 + wr*64 + m*16 + kg*4 + j;   // global row = b*2048+s
          int c = nt*128 + wc*64 + n*16 + lr;         // d
          int b = r >> 11, s = r & 2047;
          qb[(size_t)((b*HH + h) * SS + s) * DD + c] = f2bf(acc[m][n][j]);
        }
  } else if (qi == 1) {
    #pragma unroll
    for (int m = 0; m < 4; ++m)
      #pragma unroll
      for (int n = 0; n < 4; ++n)
        #pragma unroll
        for (int j = 0; j < 4; ++j) {
          int r = mt*128 + wr*64 + m*16 + kg*4 + j;
          int d = nt*128 + wc*64 + n*16 + lr;
          int b = r >> 11, srow = r & 2047;
          int bh = b*HH + h, c = srow >> 5, l31 = srow & 31;
          int kb = d >> 4, hfd = (d >> 3) & 1, e = d & 7;
          kp[(((size_t)(bh*64 + c)*16 + kb)*64 + hfd*32 + l31)*8 + e] = f2bf(acc[m][n][j]);
        }
  } else {
    int hfs = (kg >> 1) & 1, e0 = (kg & 1) * 4;
    #pragma unroll
    for (int m = 0; m < 4; ++m)
      #pragma unroll
      for (int n = 0; n < 4; ++n) {
        int r = mt*128 + wr*64 + m*16 + kg*4;         // j=0 row
        int d = nt*128 + wc*64 + n*16 + lr;
        int b = r >> 11, srow = r & 2047;
        int bh = b*HH + h, c = srow >> 5;
        int kb2 = (srow >> 4) & 1;
        int db = d >> 5, l31 = d & 31;
        union { u16 s4[4]; uint2 u2; } pk;
        #pragma unroll
        for (int j = 0; j < 4; ++j) pk.s4[j] = f2bf(acc[m][n][j]);
        *(uint2*)(vp + ((((size_t)(bh*64 + c)*8 + db)*2 + kb2)*64 + hfs*32 + l31)*8 + e0) = pk.u2;
      }
  }
}

// ---------------- attn chunk body (r12 schedule + K-batchA rotating prefetch) ----------------
// kc: this chunk's K batch A (already resident). kn: filled with next chunk's
// batch A during the softmax tail (sA/sB/kfb dead there). vf/kfb are locals.
__device__ __forceinline__ void attn_chunk(
    int c, int qt, int c1,
    const u16* __restrict__ Kp0, const u16* __restrict__ Vp0,
    int dh, int l31, int hf, int lane, const char* Qs,
    bf16x8 (&kc)[8], bf16x8 (&kn)[8],
    f32x16 (&o)[4], float& m, float& lsum) {
  const u16* kpc = Kp0 + (size_t)c * (16 * 512);
  const u16* vpc = Vp0 + (size_t)c * (16 * 512);
  // V A-frags (latency hides under QK), 32 regs
  bf16x8 vf[8];
  #pragma unroll
  for (int i = 0; i < 8; ++i)
    vf[i] = *(const bf16x8*)(vpc + (dh*8 + i)*512 + lane*8);
  __builtin_amdgcn_sched_barrier(0);

  f32x16 sA, sB;
  #pragma unroll
  for (int r = 0; r < 16; ++r) { sA[r] = 0.f; sB[r] = 0.f; }
  __builtin_amdgcn_s_setprio(1);
  #pragma unroll
  for (int kb = 0; kb < 8; ++kb) {
    bf16x8 qv = *(const bf16x8*)(Qs + kb*1024 + lane*16);
    sA = __builtin_amdgcn_mfma_f32_32x32x16_bf16(kc[kb], qv, sA, 0, 0, 0);
    if (kb == 3) __builtin_amdgcn_sched_barrier(0);
  }
  __builtin_amdgcn_s_setprio(0);
  __builtin_amdgcn_sched_barrier(0);
  // K batch B transient (kb 8..15; kc dead now)
  bf16x8 kfb[8];
  #pragma unroll
  for (int kb = 0; kb < 8; ++kb)
    kfb[kb] = *(const bf16x8*)(kpc + (8 + kb)*512 + lane*8);
  __builtin_amdgcn_sched_barrier(0);
  __builtin_amdgcn_s_setprio(1);
  #pragma unroll
  for (int kb = 0; kb < 8; ++kb) {
    bf16x8 qv = *(const bf16x8*)(Qs + (8 + kb)*1024 + lane*16);
    sB = __builtin_amdgcn_mfma_f32_32x32x16_bf16(kfb[kb], qv, sB, 0, 0, 0);
    if (kb == 3) __builtin_amdgcn_sched_barrier(0);
  }
  __builtin_amdgcn_s_setprio(0);

  float pr[16];                // scores in log2 domain
  #pragma unroll
  for (int r = 0; r < 16; ++r) pr[r] = sA[r] + sB[r];
  if (c == qt) {               // causal mask
    #pragma unroll
    for (int r = 0; r < 16; ++r) {
      int key = (r & 3) + 8*(r >> 2) + 4*hf;
      if (key > l31) pr[r] = -1e9f;
    }
  }
  // online softmax (log2 dom), stats replicated across hf halves
  float mx = pr[0];
  #pragma unroll
  for (int r = 1; r < 16; ++r) mx = fmaxf(mx, pr[r]);
  mx = fmaxf(mx, __shfl_xor(mx, 32));
  if (!__all(mx <= m + 11.5f)) {   // defer-max
    float mnew = fmaxf(m, mx);
    float al = exp2f(m - mnew);
    lsum *= al;
    #pragma unroll
    for (int j = 0; j < 4; ++j) o[j] *= al;
    m = mnew;
  }
  float psum = 0.f;
  #pragma unroll
  for (int r = 0; r < 16; ++r) { pr[r] = exp2f(pr[r] - m); psum += pr[r]; }
  psum += __shfl_xor(psum, 32);
  lsum += psum;

  // ---- prefetch next chunk's K batch A (sA/sB/kfb dead; 32 regs) ----
  if (c + 1 < c1) {
    const u16* kpn = Kp0 + (size_t)(c + 1) * (16 * 512);
    #pragma unroll
    for (int kb = 0; kb < 8; ++kb)
      kn[kb] = *(const bf16x8*)(kpn + kb*512 + lane*8);
  }

  // pack P^T -> bf16 B-frags (4 shfls via send-select)
  u32 cpk[8];
  #pragma unroll
  for (int i = 0; i < 8; ++i) {
    u32 rpk;
    asm("v_cvt_pk_bf16_f32 %0, %1, %2" : "=v"(rpk) : "v"(pr[2*i]), "v"(pr[2*i+1]));
    cpk[i] = rpk;
  }
  u32 x0 = (u32)__shfl_xor((int)(hf ? cpk[0] : cpk[2]), 32);
  u32 x1 = (u32)__shfl_xor((int)(hf ? cpk[1] : cpk[3]), 32);
  u32 x2 = (u32)__shfl_xor((int)(hf ? cpk[4] : cpk[6]), 32);
  u32 x3 = (u32)__shfl_xor((int)(hf ? cpk[5] : cpk[7]), 32);
  union { u32 w[4]; bf16x8 v; } pb0, pb1;
  pb0.w[0] = hf ? x0 : cpk[0];
  pb0.w[1] = hf ? x1 : cpk[1];
  pb0.w[2] = hf ? cpk[2] : x0;
  pb0.w[3] = hf ? cpk[3] : x1;
  pb1.w[0] = hf ? x2 : cpk[4];
  pb1.w[1] = hf ? x3 : cpk[5];
  pb1.w[2] = hf ? cpk[6] : x2;
  pb1.w[3] = hf ? cpk[7] : x3;
  // O^T += V^T P^T
  __builtin_amdgcn_s_setprio(1);
  #pragma unroll
  for (int j = 0; j < 4; ++j) {
    o[j] = __builtin_amdgcn_mfma_f32_32x32x16_bf16(vf[j*2+0], pb0.v, o[j], 0, 0, 0);
    o[j] = __builtin_amdgcn_mfma_f32_32x32x16_bf16(vf[j*2+1], pb1.v, o[j], 0, 0, 0);
  }
  __builtin_amdgcn_s_setprio(0);
}

// ---------------- flash attention (causal), register-resident ----------------
// 256 blocks (1/CU) x 512 threads (8 waves). Wave wid: ks = wid&3 (key-split-4),
// dh = wid>>2 (d-half). Q-tile in LDS. r12 chunk schedule + rotating K-batchA
// prefetch (single 32-reg extra buffer; peak arch-live <= ~120 -> no spill).
__global__ __launch_bounds__(512, 2) void attn_k(const u16* __restrict__ Qb,
                                                 const u16* __restrict__ Kp,
                                                 const u16* __restrict__ Vp,
                                                 u16* __restrict__ ctx) {
  int bid = blockIdx.x;            // 256 blocks
  int xcd = bid & 7;
  int p   = bid >> 3;              // 0..31 pair index
  int tid = threadIdx.x, wid = tid >> 6, lane = tid & 63;
  int ks = wid & 3, dh = wid >> 2;
  int l31 = lane & 31, hf = lane >> 5;

  __shared__ float Ob[32 * 256];       // O[q][d] merge buffer (swizzled)
  __shared__ float stats[4][32][2];    // per-ks {m, l} per q-row
  __shared__ u16 Qs[16 * 64 * 8];      // Q-tile frag image: [kb][lane][8]

  for (int bhp = 0; bhp < 2; ++bhp) {
    int bh = xcd + 8 * bhp;
    int b = bh >> 2, h = bh & 3;
    const u16* Q = Qb + (size_t)bh * SS * DD;
    const u16* Kp0 = Kp + (size_t)bh * 64 * (16 * 512);
    const u16* Vp0 = Vp + (size_t)bh * 64 * (16 * 512);

    for (int tp = 0; tp < 2; ++tp) {
      int qt = tp ? p : 63 - p;      // heavy tile first
      int q0 = qt * 32;

      // ---- stage Q-tile frags into LDS (wave w stages kb = 2w, 2w+1) ----
      #pragma unroll
      for (int i = 0; i < 2; ++i) {
        int kb = wid*2 + i;
        uint4 qv = *(const uint4*)(Q + (size_t)(q0 + l31) * DD + kb*16 + hf*8);
        *(uint4*)((char*)Qs + kb*1024 + lane*16) = qv;
      }
      __syncthreads();

      f32x16 o[4];                   // O^T: o[j][r] = O[q=l31][(dh*4+j)*32 + crow(r,hf)]
      #pragma unroll
      for (int j = 0; j < 4; ++j)
        #pragma unroll
        for (int r = 0; r < 16; ++r) o[j][r] = 0.f;
      float m = -1e30f, lsum = 0.f;

      int n = qt + 1;
      int c0 = (n * ks) >> 2, c1 = (n * (ks + 1)) >> 2;

      if (c0 < c1) {
        bf16x8 kA[8], kB[8];
        {
          const u16* kpc = Kp0 + (size_t)c0 * (16 * 512);
          #pragma unroll
          for (int kb = 0; kb < 8; ++kb)
            kA[kb] = *(const bf16x8*)(kpc + kb*512 + lane*8);
        }
        int c = c0;
        while (true) {
          attn_chunk(c, qt, c1, Kp0, Vp0, dh, l31, hf, lane,
                     (const char*)Qs, kA, kB, o, m, lsum);
          if (++c >= c1) break;
          attn_chunk(c, qt, c1, Kp0, Vp0, dh, l31, hf, lane,
                     (const char*)Qs, kB, kA, o, m, lsum);
          if (++c >= c1) break;
        }
      }

      // ---- merge 4 key-split partials per d-half ----
      __syncthreads();
      if (lane < 32 && wid < 4) { stats[wid][l31][0] = m; stats[wid][l31][1] = lsum; }
      __syncthreads();
      float mg = fmaxf(fmaxf(stats[0][l31][0], stats[1][l31][0]),
                       fmaxf(stats[2][l31][0], stats[3][l31][0]));
      float beta = exp2f(m - mg);
      #pragma unroll
      for (int j = 0; j < 4; ++j) o[j] *= beta;

      // rotating-region accumulate; o selected via vector ternary (stays in regs)
      #pragma unroll
      for (int tau = 0; tau < 4; ++tau) {
        int jr = (ks + tau) & 3;
        f32x16 osel = (jr == 0) ? o[0] : (jr == 1) ? o[1] : (jr == 2) ? o[2] : o[3];
        #pragma unroll
        for (int u = 0; u < 4; ++u) {
          int byteoff = l31*1024 + ((((dh*4 + jr)*128) + u*32 + hf*16) ^ ((l31 & 7) << 4));
          float* ptr = (float*)((char*)Ob + byteoff);
          f32x4 val = { osel[4*u+0], osel[4*u+1], osel[4*u+2], osel[4*u+3] };
          if (tau == 0) *(f32x4*)ptr = val;
          else {
            f32x4 old = *(f32x4*)ptr;
            *(f32x4*)ptr = old + val;
          }
        }
        __syncthreads();
      }

      // ---- final normalize + write ctx (first 256 threads) ----
      if (tid < 256) {
        int q = tid >> 3, dg = tid & 7;       // 32 q x 8 d-groups of 32
        float mgq = fmaxf(fmaxf(stats[0][q][0], stats[1][q][0]),
                          fmaxf(stats[2][q][0], stats[3][q][0]));
        float lg = exp2f(stats[0][q][0] - mgq) * stats[0][q][1]
                 + exp2f(stats[1][q][0] - mgq) * stats[1][q][1]
                 + exp2f(stats[2][q][0] - mgq) * stats[2][q][1]
                 + exp2f(stats[3][q][0] - mgq) * stats[3][q][1];
        float linv = 1.f / lg;
        u16* crow = ctx + (size_t)(b*SS + q0 + q) * EE + h*DD + dg*32;
        union { u16 s16[16]; uint4 u4[2]; } outp;
        #pragma unroll
        for (int i = 0; i < 8; ++i) {
          int byteoff = q*1024 + ((dg*128 + i*16) ^ ((q & 7) << 4));
          f32x4 v = *(const f32x4*)((const char*)Ob + byteoff);
          #pragma unroll
          for (int j = 0; j < 4; ++j) outp.s16[(i*4+j) & 15] = f2bf(v[j] * linv);
          if (i == 3) {                     // d = dg*32 + 0..15
            *(uint4*)(crow + 0) = outp.u4[0];
            *(uint4*)(crow + 8) = outp.u4[1];
          }
          if (i == 7) {                     // d = dg*32 + 16..31
            *(uint4*)(crow + 16) = outp.u4[0];
            *(uint4*)(crow + 24) = outp.u4[1];
          }
        }
      }
      __syncthreads();                      // Ob/stats/Qs safe for next phase
    }
  }
}

// ---------------- output projection + residual (round-12 mapping) ----------------
__global__ __launch_bounds__(256) void proj_gemm_k(const u16* __restrict__ ctx,
                                                   const u16* __restrict__ wot,
                                                   const float* __restrict__ x,
                                                   float* __restrict__ y) {
  __shared__ u16 As[128*64], Bs[128*64];
  int bid = blockIdx.x;                 // 512 = 64 mt x 8 nt
  int mt = bid & 63, nt = bid >> 6;
  f32x4 acc[4][4];
  gemm128(ctx, EE, wot, EE, mt*128, nt*128, EE, As, Bs, acc);
  int t = threadIdx.x, lane = t & 63, w = t >> 6;
  int wr = w >> 1, wc = w & 1, lr = lane & 15, kg = lane >> 4;
  #pragma unroll
  for (int m = 0; m < 4; ++m)
    #pragma unroll
    for (int n = 0; n < 4; ++n)
      #pragma unroll
      for (int j = 0; j < 4; ++j) {
        int r = mt*128 + wr*64 + m*16 + kg*4 + j;
        int c = nt*128 + wc*64 + n*16 + lr;
        size_t idx = (size_t)r * EE + c;
        y[idx] = acc[m][n][j] + x[idx];
      }
}

// ---------------- LayerNorm in-place on y [8192][1024] ----------------
__global__ __launch_bounds__(256) void ln_k(float* __restrict__ y,
                                            const float* __restrict__ gamma,
                                            const float* __restrict__ beta) {
  int row = blockIdx.x;
  int t = threadIdx.x;
  float4 v = *((const float4*)(y + (size_t)row * EE) + t);
  float s = v.x + v.y + v.z + v.w;
  float ss = v.x*v.x + v.y*v.y + v.z*v.z + v.w*v.w;
  #pragma unroll
  for (int off = 1; off < 64; off <<= 1) {
    s  += __shfl_xor(s, off);
    ss += __shfl_xor(ss, off);
  }
  __shared__ float rs[4], rss[4];
  int w = t >> 6, lane = t & 63;
  if (lane == 0) { rs[w] = s; rss[w] = ss; }
  __syncthreads();
  s  = rs[0] + rs[1] + rs[2] + rs[3];
  ss = rss[0] + rss[1] + rss[2] + rss[3];
  float mean = s * (1.f / EE);
  float var  = ss * (1.f / EE) - mean * mean;
  float rstd = rsqrtf(var + 1e-6f);
  float4 g  = *((const float4*)gamma + t);
  float4 be = *((const float4*)beta + t);
  float4 ov;
  ov.x = (v.x - mean) * rstd * g.x + be.x;
  ov.y = (v.y - mean) * rstd * g.y + be.y;
  ov.z = (v.z - mean) * rstd * g.z + be.z;
  ov.w = (v.w - mean) * rstd * g.w + be.w;
  *((float4*)(y + (size_t)row * EE) + t) = ov;
}

extern "C" void kernel_launch(void* const* d_in, const int* in_sizes, int n_in,
                              void* d_out, int out_size, void* d_ws, size_t ws_size,
                              hipStream_t stream) {
  const float* x      = (const float*)d_in[0];
  const float* qkv_w  = (const float*)d_in[1];
  const float* out_w  = (const float*)d_in[2];
  const float* gamma  = (const float*)d_in[3];
  const float* beta   = (const float*)d_in[4];
  float* out = (float*)d_out;
  char* ws = (char*)d_ws;

  u16* xb  = (u16*)(ws);                       // 8192*1024 bf16 (16.78 MB)
  u16* ctx = xb;                               // reuse after QKV
  u16* wqt = (u16*)(ws + 16777216);            // [12][256][1024]
  u16* wot = (u16*)(ws + 23068672);            // [1024][1024]
  u16* Qb  = (u16*)(ws + 25165824);            // Q [b][h][s][d]
  u16* Kpb = Qb + (size_t)BB*HH*SS*DD;         // K frag-packed
  u16* Vpb = Kpb + (size_t)BB*HH*SS*DD;        // V frag-packed

  // softmax scale folded into Q weights, converted to log2 domain:
  // exp(s/32) = 2^(s * 0.03125 * log2(e))
  const float QSC = 0.03125f * 1.44269504088896340736f;

  cast_bf16_k<<<8192, 256, 0, stream>>>(x, xb, (BB*SS*EE)/4);
  transpose_cast_k<<<dim3(8, 32, 12), dim3(32, 8), 0, stream>>>(qkv_w, wqt, EE, DD, QSC);
  transpose_cast_k<<<dim3(32, 32, 1), dim3(32, 8), 0, stream>>>(out_w, wot, EE, EE, 1.0f);
  qkv_gemm_k<<<1536, 256, 0, stream>>>(xb, wqt, Qb, Kpb, Vpb);
  attn_k<<<256, 512, 0, stream>>>(Qb, Kpb, Vpb, ctx);
  proj_gemm_k<<<512, 256, 0, stream>>>(ctx, wot, x, out);
  ln_k<<<8192, 256, 0, stream>>>(out, gamma, beta);
}

// Round 17
// 201.243 us; speedup vs baseline: 1.2390x; 1.2390x over previous
//
#include <hip/hip_runtime.h>

typedef __attribute__((ext_vector_type(8))) __bf16 bf16x8;
typedef __attribute__((ext_vector_type(4))) float f32x4;
typedef __attribute__((ext_vector_type(16))) float f32x16;
typedef unsigned short u16;
typedef unsigned int u32;

#define BB 4
#define SS 2048
#define EE 1024
#define HH 4
#define DD 256

#define GLOAD_LDS(g, l) __builtin_amdgcn_global_load_lds( \
    (const __attribute__((address_space(1))) unsigned int*)(g), \
    (__attribute__((address_space(3))) unsigned int*)(l), 16, 0, 0)

__device__ __forceinline__ u16 f2bf(float f) {
  unsigned int u = __float_as_uint(f);
  u = (u + 0x7FFFu + ((u >> 16) & 1u)) >> 16;   // RNE
  return (u16)u;
}

// ---------------- cast f32 -> bf16 (vectorized) ----------------
__global__ __launch_bounds__(256) void cast_bf16_k(const float* __restrict__ in,
                                                   u16* __restrict__ out, int n4) {
  int i = blockIdx.x * 256 + threadIdx.x;
  if (i >= n4) return;
  float4 v = ((const float4*)in)[i];
  union { u16 s[4]; uint2 u; } o;
  o.s[0] = f2bf(v.x); o.s[1] = f2bf(v.y); o.s[2] = f2bf(v.z); o.s[3] = f2bf(v.w);
  ((uint2*)out)[i] = o.u;
}

// ---------------- transpose + cast: in[R][C] f32 -> out[C][R] bf16 ----------------
// scale_q applied when blockIdx.z < 4 (Q-head weights: fold softmax scale, log2 dom).
__global__ __launch_bounds__(256) void transpose_cast_k(const float* __restrict__ in,
                                                        u16* __restrict__ out, int R, int C,
                                                        float scale_q) {
  __shared__ float tile[32][33];
  size_t moff = (size_t)blockIdx.z * R * C;
  in += moff; out += moff;
  float sc = (blockIdx.z < 4) ? scale_q : 1.0f;
  int c0 = blockIdx.x * 32, r0 = blockIdx.y * 32;
  int tx = threadIdx.x, ty = threadIdx.y;   // 32 x 8
  #pragma unroll
  for (int i = 0; i < 4; ++i)
    tile[ty + 8*i][tx] = in[(size_t)(r0 + ty + 8*i) * C + c0 + tx];
  __syncthreads();
  #pragma unroll
  for (int i = 0; i < 4; ++i)
    out[(size_t)(c0 + ty + 8*i) * R + r0 + tx] = f2bf(tile[tx][ty + 8*i] * sc);
}

// ---------------- 128x128 bf16 GEMM core: C = A[M][K] * Bt[N][K]^T ----------------
__device__ __forceinline__ void gemm128(const u16* __restrict__ A, int lda,
                                        const u16* __restrict__ Bt, int ldb,
                                        int row0, int col0, int K,
                                        u16* As, u16* Bs, f32x4 acc[4][4]) {
  int t = threadIdx.x;
  int lane = t & 63, w = t >> 6;
  int wr = w >> 1, wc = w & 1;
  int lr = lane & 15, kg = lane >> 4;
  f32x4 z = {0.f, 0.f, 0.f, 0.f};
  #pragma unroll
  for (int m = 0; m < 4; ++m)
    #pragma unroll
    for (int n = 0; n < 4; ++n) acc[m][n] = z;
  for (int kt = 0; kt < K; kt += 64) {
    __syncthreads();
    #pragma unroll
    for (int it = 0; it < 4; ++it) {
      int Lb = it*4096 + w*1024 + lane*16;       // dest byte within 128x64 tile
      int row = Lb >> 7;
      int scb = ((Lb >> 4) & 7) ^ (row & 7);     // pre-swizzled source col-block
      GLOAD_LDS(A  + (size_t)(row0 + row) * lda + kt + scb*8,
                (char*)As + it*4096 + w*1024);
      GLOAD_LDS(Bt + (size_t)(col0 + row) * ldb + kt + scb*8,
                (char*)Bs + it*4096 + w*1024);
    }
    __syncthreads();
    __builtin_amdgcn_s_setprio(1);
    #pragma unroll
    for (int kk = 0; kk < 2; ++kk) {
      bf16x8 af[4], bfr[4];
      #pragma unroll
      for (int m = 0; m < 4; ++m) {
        int row = wr*64 + m*16 + lr;
        int bo = (row << 7) + ((((kk << 6) + (kg << 4))) ^ ((row & 7) << 4));
        af[m] = *(const bf16x8*)((const char*)As + bo);
      }
      #pragma unroll
      for (int n = 0; n < 4; ++n) {
        int row = wc*64 + n*16 + lr;
        int bo = (row << 7) + ((((kk << 6) + (kg << 4))) ^ ((row & 7) << 4));
        bfr[n] = *(const bf16x8*)((const char*)Bs + bo);
      }
      #pragma unroll
      for (int m = 0; m < 4; ++m)
        #pragma unroll
        for (int n = 0; n < 4; ++n)
          acc[m][n] = __builtin_amdgcn_mfma_f32_16x16x32_bf16(af[m], bfr[n], acc[m][n], 0, 0, 0);
    }
    __builtin_amdgcn_s_setprio(0);
  }
}

// ---------------- QKV projection (mt fast -> XCD-affine A panels) ----------------
__global__ __launch_bounds__(256) void qkv_gemm_k(const u16* __restrict__ xb,
                                                  const u16* __restrict__ wt,
                                                  u16* __restrict__ qb,
                                                  u16* __restrict__ kp,
                                                  u16* __restrict__ vp) {
  __shared__ u16 As[128*64], Bs[128*64];
  int bid = blockIdx.x;
  int mh = bid >> 7;               // 0..11  (qkvi*4 + h)
  int tt = bid & 127;
  int mt = tt & 63, nt = tt >> 6;  // 64 M-tiles, 2 N-tiles
  f32x4 acc[4][4];
  gemm128(xb, EE, wt + (size_t)mh * DD * EE, EE, mt*128, nt*128, EE, As, Bs, acc);
  int t = threadIdx.x, lane = t & 63, w = t >> 6;
  int wr = w >> 1, wc = w & 1, lr = lane & 15, kg = lane >> 4;
  int qi = mh >> 2, h = mh & 3;
  if (qi == 0) {
    #pragma unroll
    for (int m = 0; m < 4; ++m)
      #pragma unroll
      for (int n = 0; n < 4; ++n)
        #pragma unroll
        for (int j = 0; j < 4; ++j) {
          int r = mt*128 + wr*64 + m*16 + kg*4 + j;   // global row = b*2048+s
          int c = nt*128 + wc*64 + n*16 + lr;         // d
          int b = r >> 11, s = r & 2047;
          qb[(size_t)((b*HH + h) * SS + s) * DD + c] = f2bf(acc[m][n][j]);
        }
  } else if (qi == 1) {
    #pragma unroll
    for (int m = 0; m < 4; ++m)
      #pragma unroll
      for (int n = 0; n < 4; ++n)
        #pragma unroll
        for (int j = 0; j < 4; ++j) {
          int r = mt*128 + wr*64 + m*16 + kg*4 + j;
          int d = nt*128 + wc*64 + n*16 + lr;
          int b = r >> 11, srow = r & 2047;
          int bh = b*HH + h, c = srow >> 5, l31 = srow & 31;
          int kb = d >> 4, hfd = (d >> 3) & 1, e = d & 7;
          kp[(((size_t)(bh*64 + c)*16 + kb)*64 + hfd*32 + l31)*8 + e] = f2bf(acc[m][n][j]);
        }
  } else {
    int hfs = (kg >> 1) & 1, e0 = (kg & 1) * 4;
    #pragma unroll
    for (int m = 0; m < 4; ++m)
      #pragma unroll
      for (int n = 0; n < 4; ++n) {
        int r = mt*128 + wr*64 + m*16 + kg*4;         // j=0 row
        int d = nt*128 + wc*64 + n*16 + lr;
        int b = r >> 11, srow = r & 2047;
        int bh = b*HH + h, c = srow >> 5;
        int kb2 = (srow >> 4) & 1;
        int db = d >> 5, l31 = d & 31;
        union { u16 s4[4]; uint2 u2; } pk;
        #pragma unroll
        for (int j = 0; j < 4; ++j) pk.s4[j] = f2bf(acc[m][n][j]);
        *(uint2*)(vp + ((((size_t)(bh*64 + c)*8 + db)*2 + kb2)*64 + hfs*32 + l31)*8 + e0) = pk.u2;
      }
  }
}

// ---------------- flash attention (causal), register-resident (r12 body) ----------------
// 256 blocks (1/CU) x 512 threads (8 waves). Wave wid: ks = wid&3 (key-split-4),
// dh = wid>>2 (d-half). Q-tile in LDS (shared). kf batched 8+8 with
// sched_barrier(0) fences so peak arch-live stays <= 128 (no spill at 2 w/SIMD).
// Block p on XCD x: for bh in {x, x+8} (ONE bh hot per XCD -> 2MB L2-resident),
// q-tiles 63-p then p. Scores pre-scaled in log2 domain (folded into Q weights).
__global__ __launch_bounds__(512, 2) void attn_k(const u16* __restrict__ Qb,
                                                 const u16* __restrict__ Kp,
                                                 const u16* __restrict__ Vp,
                                                 u16* __restrict__ ctx) {
  int bid = blockIdx.x;            // 256 blocks
  int xcd = bid & 7;
  int p   = bid >> 3;              // 0..31 pair index
  int tid = threadIdx.x, wid = tid >> 6, lane = tid & 63;
  int ks = wid & 3, dh = wid >> 2;
  int l31 = lane & 31, hf = lane >> 5;

  __shared__ float Ob[32 * 256];       // O[q][d] merge buffer (swizzled)
  __shared__ float stats[4][32][2];    // per-ks {m, l} per q-row
  __shared__ u16 Qs[16 * 64 * 8];      // Q-tile frag image: [kb][lane][8]

  for (int bhp = 0; bhp < 2; ++bhp) {
    int bh = xcd + 8 * bhp;
    int b = bh >> 2, h = bh & 3;
    const u16* Q = Qb + (size_t)bh * SS * DD;
    size_t bh64 = (size_t)bh * 64;

    for (int tp = 0; tp < 2; ++tp) {
      int qt = tp ? p : 63 - p;      // heavy tile first
      int q0 = qt * 32;

      // ---- stage Q-tile frags into LDS (wave w stages kb = 2w, 2w+1) ----
      #pragma unroll
      for (int i = 0; i < 2; ++i) {
        int kb = wid*2 + i;
        uint4 qv = *(const uint4*)(Q + (size_t)(q0 + l31) * DD + kb*16 + hf*8);
        *(uint4*)((char*)Qs + kb*1024 + lane*16) = qv;
      }
      __syncthreads();

      f32x16 o[4];                   // O^T: o[j][r] = O[q=l31][(dh*4+j)*32 + crow(r,hf)]
      #pragma unroll
      for (int j = 0; j < 4; ++j)
        #pragma unroll
        for (int r = 0; r < 16; ++r) o[j][r] = 0.f;
      float m = -1e30f, lsum = 0.f;

      int n = qt + 1;
      int c0 = (n * ks) >> 2, c1 = (n * (ks + 1)) >> 2;

      for (int c = c0; c < c1; ++c) {
        const u16* kpc = Kp + (bh64 + c) * (16 * 512);
        const u16* vpc = Vp + (bh64 + c) * (16 * 512);
        // V A-frags issued first (latency hides under QK + softmax)
        bf16x8 vf[8];                // i = j*2 + kb2, global db8 = dh*4 + j
        #pragma unroll
        for (int i = 0; i < 8; ++i)
          vf[i] = *(const bf16x8*)(vpc + (dh*8 + i)*512 + lane*8);
        // K batch A (8 frags, 32 regs)
        bf16x8 kfa[8];
        #pragma unroll
        for (int kb = 0; kb < 8; ++kb)
          kfa[kb] = *(const bf16x8*)(kpc + kb*512 + lane*8);
        __builtin_amdgcn_sched_barrier(0);

        f32x16 sA, sB;
        #pragma unroll
        for (int r = 0; r < 16; ++r) { sA[r] = 0.f; sB[r] = 0.f; }
        __builtin_amdgcn_s_setprio(1);
        #pragma unroll
        for (int kb = 0; kb < 8; ++kb) {
          bf16x8 qv = *(const bf16x8*)((const char*)Qs + kb*1024 + lane*16);
          sA = __builtin_amdgcn_mfma_f32_32x32x16_bf16(kfa[kb], qv, sA, 0, 0, 0);
          if (kb == 3) __builtin_amdgcn_sched_barrier(0);
        }
        __builtin_amdgcn_s_setprio(0);
        __builtin_amdgcn_sched_barrier(0);
        // K batch B (kfa dead now)
        bf16x8 kfb[8];
        #pragma unroll
        for (int kb = 0; kb < 8; ++kb)
          kfb[kb] = *(const bf16x8*)(kpc + (8 + kb)*512 + lane*8);
        __builtin_amdgcn_sched_barrier(0);
        __builtin_amdgcn_s_setprio(1);
        #pragma unroll
        for (int kb = 0; kb < 8; ++kb) {
          bf16x8 qv = *(const bf16x8*)((const char*)Qs + (8 + kb)*1024 + lane*16);
          sB = __builtin_amdgcn_mfma_f32_32x32x16_bf16(kfb[kb], qv, sB, 0, 0, 0);
          if (kb == 3) __builtin_amdgcn_sched_barrier(0);
        }
        __builtin_amdgcn_s_setprio(0);

        float pr[16];                // scores already in log2 domain
        #pragma unroll
        for (int r = 0; r < 16; ++r) pr[r] = sA[r] + sB[r];
        if (c == qt) {               // causal mask (ks==3 only reaches c==qt)
          #pragma unroll
          for (int r = 0; r < 16; ++r) {
            int key = (r & 3) + 8*(r >> 2) + 4*hf;
            if (key > l31) pr[r] = -1e9f;
          }
        }
        // online softmax (log2 dom), stats replicated across hf halves
        float mx = pr[0];
        #pragma unroll
        for (int r = 1; r < 16; ++r) mx = fmaxf(mx, pr[r]);
        mx = fmaxf(mx, __shfl_xor(mx, 32));
        // defer-max: rescale only when max grew beyond threshold
        if (!__all(mx <= m + 11.5f)) {
          float mnew = fmaxf(m, mx);
          float al = exp2f(m - mnew);
          lsum *= al;
          #pragma unroll
          for (int j = 0; j < 4; ++j) o[j] *= al;
          m = mnew;
        }
        float psum = 0.f;
        #pragma unroll
        for (int r = 0; r < 16; ++r) { pr[r] = exp2f(pr[r] - m); psum += pr[r]; }
        psum += __shfl_xor(psum, 32);
        lsum += psum;
        // pack P^T -> bf16 B-frags (4 shfls via send-select)
        u32 cpk[8];
        #pragma unroll
        for (int i = 0; i < 8; ++i) {
          u32 rpk;
          asm("v_cvt_pk_bf16_f32 %0, %1, %2" : "=v"(rpk) : "v"(pr[2*i]), "v"(pr[2*i+1]));
          cpk[i] = rpk;
        }
        u32 x0 = (u32)__shfl_xor((int)(hf ? cpk[0] : cpk[2]), 32);
        u32 x1 = (u32)__shfl_xor((int)(hf ? cpk[1] : cpk[3]), 32);
        u32 x2 = (u32)__shfl_xor((int)(hf ? cpk[4] : cpk[6]), 32);
        u32 x3 = (u32)__shfl_xor((int)(hf ? cpk[5] : cpk[7]), 32);
        union { u32 w[4]; bf16x8 v; } pb0, pb1;
        pb0.w[0] = hf ? x0 : cpk[0];
        pb0.w[1] = hf ? x1 : cpk[1];
        pb0.w[2] = hf ? cpk[2] : x0;
        pb0.w[3] = hf ? cpk[3] : x1;
        pb1.w[0] = hf ? x2 : cpk[4];
        pb1.w[1] = hf ? x3 : cpk[5];
        pb1.w[2] = hf ? cpk[6] : x2;
        pb1.w[3] = hf ? cpk[7] : x3;
        // O^T += V^T P^T (this wave's 4 db blocks)
        __builtin_amdgcn_s_setprio(1);
        #pragma unroll
        for (int j = 0; j < 4; ++j) {
          o[j] = __builtin_amdgcn_mfma_f32_32x32x16_bf16(vf[j*2+0], pb0.v, o[j], 0, 0, 0);
          o[j] = __builtin_amdgcn_mfma_f32_32x32x16_bf16(vf[j*2+1], pb1.v, o[j], 0, 0, 0);
        }
        __builtin_amdgcn_s_setprio(0);
      }

      // ---- merge 4 key-split partials per d-half ----
      __syncthreads();
      if (lane < 32 && wid < 4) { stats[wid][l31][0] = m; stats[wid][l31][1] = lsum; }
      __syncthreads();
      float mg = fmaxf(fmaxf(stats[0][l31][0], stats[1][l31][0]),
                       fmaxf(stats[2][l31][0], stats[3][l31][0]));
      float beta = exp2f(m - mg);
      #pragma unroll
      for (int j = 0; j < 4; ++j) o[j] *= beta;

      // rotating-region accumulate; o selected via vector ternary (stays in regs)
      #pragma unroll
      for (int tau = 0; tau < 4; ++tau) {
        int jr = (ks + tau) & 3;
        f32x16 osel = (jr == 0) ? o[0] : (jr == 1) ? o[1] : (jr == 2) ? o[2] : o[3];
        #pragma unroll
        for (int u = 0; u < 4; ++u) {
          int byteoff = l31*1024 + ((((dh*4 + jr)*128) + u*32 + hf*16) ^ ((l31 & 7) << 4));
          float* ptr = (float*)((char*)Ob + byteoff);
          f32x4 val = { osel[4*u+0], osel[4*u+1], osel[4*u+2], osel[4*u+3] };
          if (tau == 0) *(f32x4*)ptr = val;
          else {
            f32x4 old = *(f32x4*)ptr;
            *(f32x4*)ptr = old + val;
          }
        }
        __syncthreads();
      }

      // ---- final normalize + write ctx (first 256 threads) ----
      if (tid < 256) {
        int q = tid >> 3, dg = tid & 7;       // 32 q x 8 d-groups of 32
        float mgq = fmaxf(fmaxf(stats[0][q][0], stats[1][q][0]),
                          fmaxf(stats[2][q][0], stats[3][q][0]));
        float lg = exp2f(stats[0][q][0] - mgq) * stats[0][q][1]
                 + exp2f(stats[1][q][0] - mgq) * stats[1][q][1]
                 + exp2f(stats[2][q][0] - mgq) * stats[2][q][1]
                 + exp2f(stats[3][q][0] - mgq) * stats[3][q][1];
        float linv = 1.f / lg;
        u16* crow = ctx + (size_t)(b*SS + q0 + q) * EE + h*DD + dg*32;
        union { u16 s16[16]; uint4 u4[2]; } outp;
        #pragma unroll
        for (int i = 0; i < 8; ++i) {
          int byteoff = q*1024 + ((dg*128 + i*16) ^ ((q & 7) << 4));
          f32x4 v = *(const f32x4*)((const char*)Ob + byteoff);
          #pragma unroll
          for (int j = 0; j < 4; ++j) outp.s16[(i*4+j) & 15] = f2bf(v[j] * linv);
          if (i == 3) {                     // d = dg*32 + 0..15
            *(uint4*)(crow + 0) = outp.u4[0];
            *(uint4*)(crow + 8) = outp.u4[1];
          }
          if (i == 7) {                     // d = dg*32 + 16..31
            *(uint4*)(crow + 16) = outp.u4[0];
            *(uint4*)(crow + 24) = outp.u4[1];
          }
        }
      }
      __syncthreads();                      // Ob/stats/Qs safe for next phase
    }
  }
}

// ---------------- output projection + residual (mt fast mapping) ----------------
__global__ __launch_bounds__(256) void proj_gemm_k(const u16* __restrict__ ctx,
                                                   const u16* __restrict__ wot,
                                                   const float* __restrict__ x,
                                                   float* __restrict__ y) {
  __shared__ u16 As[128*64], Bs[128*64];
  int bid = blockIdx.x;                 // 512 = 64 mt x 8 nt
  int mt = bid & 63, nt = bid >> 6;
  f32x4 acc[4][4];
  gemm128(ctx, EE, wot, EE, mt*128, nt*128, EE, As, Bs, acc);
  int t = threadIdx.x, lane = t & 63, w = t >> 6;
  int wr = w >> 1, wc = w & 1, lr = lane & 15, kg = lane >> 4;
  #pragma unroll
  for (int m = 0; m < 4; ++m)
    #pragma unroll
    for (int n = 0; n < 4; ++n)
      #pragma unroll
      for (int j = 0; j < 4; ++j) {
        int r = mt*128 + wr*64 + m*16 + kg*4 + j;
        int c = nt*128 + wc*64 + n*16 + lr;
        size_t idx = (size_t)r * EE + c;
        y[idx] = acc[m][n][j] + x[idx];
      }
}

// ---------------- LayerNorm in-place on y [8192][1024] ----------------
__global__ __launch_bounds__(256) void ln_k(float* __restrict__ y,
                                            const float* __restrict__ gamma,
                                            const float* __restrict__ beta) {
  int row = blockIdx.x;
  int t = threadIdx.x;
  float4 v = *((const float4*)(y + (size_t)row * EE) + t);
  float s = v.x + v.y + v.z + v.w;
  float ss = v.x*v.x + v.y*v.y + v.z*v.z + v.w*v.w;
  #pragma unroll
  for (int off = 1; off < 64; off <<= 1) {
    s  += __shfl_xor(s, off);
    ss += __shfl_xor(ss, off);
  }
  __shared__ float rs[4], rss[4];
  int w = t >> 6, lane = t & 63;
  if (lane == 0) { rs[w] = s; rss[w] = ss; }
  __syncthreads();
  s  = rs[0] + rs[1] + rs[2] + rs[3];
  ss = rss[0] + rss[1] + rss[2] + rss[3];
  float mean = s * (1.f / EE);
  float var  = ss * (1.f / EE) - mean * mean;
  float rstd = rsqrtf(var + 1e-6f);
  float4 g  = *((const float4*)gamma + t);
  float4 be = *((const float4*)beta + t);
  float4 ov;
  ov.x = (v.x - mean) * rstd * g.x + be.x;
  ov.y = (v.y - mean) * rstd * g.y + be.y;
  ov.z = (v.z - mean) * rstd * g.z + be.z;
  ov.w = (v.w - mean) * rstd * g.w + be.w;
  *((float4*)(y + (size_t)row * EE) + t) = ov;
}

extern "C" void kernel_launch(void* const* d_in, const int* in_sizes, int n_in,
                              void* d_out, int out_size, void* d_ws, size_t ws_size,
                              hipStream_t stream) {
  const float* x      = (const float*)d_in[0];
  const float* qkv_w  = (const float*)d_in[1];
  const float* out_w  = (const float*)d_in[2];
  const float* gamma  = (const float*)d_in[3];
  const float* beta   = (const float*)d_in[4];
  float* out = (float*)d_out;
  char* ws = (char*)d_ws;

  u16* xb  = (u16*)(ws);                       // 8192*1024 bf16 (16.78 MB)
  u16* ctx = xb;                               // reuse after QKV
  u16* wqt = (u16*)(ws + 16777216);            // [12][256][1024]
  u16* wot = (u16*)(ws + 23068672);            // [1024][1024]
  u16* Qb  = (u16*)(ws + 25165824);            // Q [b][h][s][d]
  u16* Kpb = Qb + (size_t)BB*HH*SS*DD;         // K frag-packed
  u16* Vpb = Kpb + (size_t)BB*HH*SS*DD;        // V frag-packed

  // softmax scale folded into Q weights, converted to log2 domain:
  // exp(s/32) = 2^(s * 0.03125 * log2(e))
  const float QSC = 0.03125f * 1.44269504088896340736f;

  cast_bf16_k<<<8192, 256, 0, stream>>>(x, xb, (BB*SS*EE)/4);
  transpose_cast_k<<<dim3(8, 32, 12), dim3(32, 8), 0, stream>>>(qkv_w, wqt, EE, DD, QSC);
  transpose_cast_k<<<dim3(32, 32, 1), dim3(32, 8), 0, stream>>>(out_w, wot, EE, EE, 1.0f);
  qkv_gemm_k<<<1536, 256, 0, stream>>>(xb, wqt, Qb, Kpb, Vpb);
  attn_k<<<256, 512, 0, stream>>>(Qb, Kpb, Vpb, ctx);
  proj_gemm_k<<<512, 256, 0, stream>>>(ctx, wot, x, out);
  ln_k<<<8192, 256, 0, stream>>>(out, gamma, beta);
}